// Round 2
// baseline (572.252 us; speedup 1.0000x reference)
//
#include <hip/hip_runtime.h>
#include <stdint.h>

#define N_ROWS 4096
#define F_DIM  2048
#define B_DIM  2048
#define K_DIM  4096   // F (h part) + B (behavior part)

typedef __attribute__((ext_vector_type(8))) __bf16 bf16x8;
typedef __attribute__((ext_vector_type(4))) float  f32x4;
typedef unsigned short u16;

__device__ __forceinline__ u16 f2bf(float x) {
  unsigned int u = __float_as_uint(x);
  u += 0x7fffu + ((u >> 16) & 1u);   // RNE
  return (u16)(u >> 16);
}

__device__ __forceinline__ void async_copy16(const void* g, void* l) {
  __builtin_amdgcn_global_load_lds(
      (const __attribute__((address_space(1))) void*)g,
      (__attribute__((address_space(3))) void*)l, 16, 0, 0);
}

__device__ __forceinline__ float sigmoid_f(float x) {
  return 1.0f / (1.0f + __expf(-x));
}
__device__ __forceinline__ float tanh_f(float x) {
  float e2 = __expf(2.0f * x);
  return 1.0f - 2.0f / (e2 + 1.0f);
}

// ---------------- pack_x: Xc[n][k] = bf16( k<F ? h0[n][k] : behavior[n][k-F] )
__global__ __launch_bounds__(256) void pack_x_kernel(
    const float* __restrict__ h0, const float* __restrict__ behavior,
    u16* __restrict__ Xc)
{
  int tid = blockIdx.x * 256 + threadIdx.x;  // one thread = 8 consecutive k
  int row = tid >> 9;                        // K_DIM/8 = 512 octets per row
  int k0  = (tid & 511) * 8;
  const float* src = (k0 < F_DIM) ? (h0 + (size_t)row * F_DIM + k0)
                                  : (behavior + (size_t)row * B_DIM + (k0 - F_DIM));
  const float4* s4 = (const float4*)src;
  float4 a = s4[0], b = s4[1];
  uint4 o;
  o.x = (unsigned)f2bf(a.x) | ((unsigned)f2bf(a.y) << 16);
  o.y = (unsigned)f2bf(a.z) | ((unsigned)f2bf(a.w) << 16);
  o.z = (unsigned)f2bf(b.x) | ((unsigned)f2bf(b.y) << 16);
  o.w = (unsigned)f2bf(b.z) | ((unsigned)f2bf(b.w) << 16);
  *(uint4*)(Xc + (size_t)tid * 8) = o;
}

// ---------------- pack_w v2: WT[g][f][k] = bf16( k<F ? W?_h[k][f] : W?_x[k-F][f] )
// 64x64 tile per block. float4 coalesced reads -> LDS transpose (pad 65,
// both phases 2-way-bank = free) -> 16B uint4 stores (8 k-contiguous bf16).
__global__ __launch_bounds__(256) void pack_w_kernel(
    const float* __restrict__ wi_h, const float* __restrict__ wi_x,
    const float* __restrict__ wf_h, const float* __restrict__ wf_x,
    const float* __restrict__ wg_h, const float* __restrict__ wg_x,
    const float* __restrict__ wo_h, const float* __restrict__ wo_x,
    u16* __restrict__ WT)
{
  __shared__ float tileT[64 * 65];  // tileT[f_local][k_local], pad 65
  int g = blockIdx.z;
  const float* Wh = (g == 0) ? wi_h : (g == 1) ? wf_h : (g == 2) ? wg_h : wo_h;
  const float* Wx = (g == 0) ? wi_x : (g == 1) ? wf_x : (g == 2) ? wg_x : wo_x;
  int fb = blockIdx.x * 64;   // feature (output-col) tile base
  int kb = blockIdx.y * 64;   // k tile base (block-uniform h/x split: 64 | 2048)
  const float* W = (kb < F_DIM) ? Wh : Wx;
  int kofs = (kb < F_DIM) ? kb : (kb - F_DIM);

  int t  = threadIdx.x;
  int c4 = t & 15;         // float4 column within f-tile
  int kl = t >> 4;         // 0..15
#pragma unroll
  for (int r = 0; r < 4; ++r) {
    int k_l = kl + r * 16;  // 0..63
    float4 v = *(const float4*)(W + (size_t)(kofs + k_l) * F_DIM + fb + c4 * 4);
    tileT[(c4 * 4 + 0) * 65 + k_l] = v.x;
    tileT[(c4 * 4 + 1) * 65 + k_l] = v.y;
    tileT[(c4 * 4 + 2) * 65 + k_l] = v.z;
    tileT[(c4 * 4 + 3) * 65 + k_l] = v.w;
  }
  __syncthreads();
#pragma unroll
  for (int it = 0; it < 2; ++it) {
    int idx = it * 256 + t;
    int f_l = idx >> 3;          // 0..63
    int k8  = (idx & 7) * 8;     // 0..56
    const float* s = tileT + f_l * 65 + k8;
    uint4 o;
    o.x = (unsigned)f2bf(s[0]) | ((unsigned)f2bf(s[1]) << 16);
    o.y = (unsigned)f2bf(s[2]) | ((unsigned)f2bf(s[3]) << 16);
    o.z = (unsigned)f2bf(s[4]) | ((unsigned)f2bf(s[5]) << 16);
    o.w = (unsigned)f2bf(s[6]) | ((unsigned)f2bf(s[7]) << 16);
    *(uint4*)(WT + ((size_t)g * F_DIM + fb + f_l) * K_DIM + kb + k8) = o;
  }
}

// ---------------- fused 4-gate GEMM + LSTM epilogue
// Block: 256 thr (4 waves). Output tile: 64 rows x 32 cols, all 4 gates
// (= 64x128 effective). Grid 64x64 = 4096 blocks (~6 resident/CU).
// Wave w -> rows [16w, 16w+16). Per wave/gate: 1x2 frags of 16x16 (mfma 16x16x32).
// LDS: As[64][64] bf16 (8KB), Bs[4][32][64] bf16 (16KB), XOR-octet swizzled.
__global__ __launch_bounds__(256) void lstm_gemm_kernel(
    const u16* __restrict__ Xc, const u16* __restrict__ WT,
    const float* __restrict__ c0,
    const float* __restrict__ bi, const float* __restrict__ bff,
    const float* __restrict__ bg, const float* __restrict__ bo,
    float* __restrict__ out)
{
  __shared__ u16 As[64 * 64];       // 8 KB
  __shared__ u16 Bs[4 * 32 * 64];   // 16 KB

  const int tid  = threadIdx.x;
  const int lane = tid & 63;
  const int wv   = tid >> 6;
  const int bm   = blockIdx.x;  // rows bm*64  (x fast-varying -> B-tile L2 reuse)
  const int bn   = blockIdx.y;  // cols bn*32

  // ---- staging descriptors (16B chunks; XOR-octet swizzle vs row&7)
  const u16* agp[2];
  const u16* bgp[4];
#pragma unroll
  for (int j = 0; j < 2; ++j) {  // A: chunk c = j*256+tid -> row c/8, slot c%8
    int c = j * 256 + tid;
    int r = c >> 3, s = c & 7, o = s ^ (r & 7);
    agp[j] = Xc + (size_t)(bm * 64 + r) * K_DIM + o * 8;
  }
#pragma unroll
  for (int j = 0; j < 4; ++j) {  // B: gate j, row tid/8, slot tid%8
    int r = tid >> 3, s = tid & 7, o = s ^ (r & 7);
    bgp[j] = WT + ((size_t)j * F_DIM + bn * 32 + r) * K_DIM + o * 8;
  }
  const unsigned ubase = (unsigned)(tid & ~63) * 16u;  // wave-uniform LDS byte offset

  f32x4 acc[4][2];
  const f32x4 zero = {0.f, 0.f, 0.f, 0.f};
#pragma unroll
  for (int g = 0; g < 4; ++g)
#pragma unroll
    for (int cf = 0; cf < 2; ++cf) acc[g][cf] = zero;

  const int q = lane >> 4, ln15 = lane & 15;

  for (int kt = 0; kt < 64; ++kt) {
#pragma unroll
    for (int j = 0; j < 2; ++j)
      async_copy16(agp[j], (char*)As + j * 4096 + ubase);
#pragma unroll
    for (int j = 0; j < 4; ++j)
      async_copy16(bgp[j], (char*)Bs + j * 4096 + ubase);
#pragma unroll
    for (int j = 0; j < 2; ++j) agp[j] += 64;
#pragma unroll
    for (int j = 0; j < 4; ++j) bgp[j] += 64;
    __syncthreads();  // compiler drains vmcnt here -> staging complete

#pragma unroll
    for (int c = 0; c < 2; ++c) {  // two k-chunks of 32 within the 64-k tile
      bf16x8 af;
      {
        int m = wv * 16 + ln15;
        int o = c * 4 + q;
        int s = o ^ (m & 7);
        af = *(const bf16x8*)(As + m * 64 + s * 8);
      }
      bf16x8 bfr[4][2];
#pragma unroll
      for (int g = 0; g < 4; ++g)
#pragma unroll
        for (int cf = 0; cf < 2; ++cf) {
          int n = cf * 16 + ln15;
          int o = c * 4 + q;
          int s = o ^ (n & 7);
          bfr[g][cf] = *(const bf16x8*)(Bs + g * 2048 + n * 64 + s * 8);
        }
#pragma unroll
      for (int g = 0; g < 4; ++g)
#pragma unroll
        for (int cf = 0; cf < 2; ++cf)
          acc[g][cf] = __builtin_amdgcn_mfma_f32_16x16x32_bf16(
              af, bfr[g][cf], acc[g][cf], 0, 0, 0);
    }
    __syncthreads();  // all waves done reading before next overwrite
  }

  // ---- epilogue: C/D layout col = lane&15, row = quad*4 + reg
#pragma unroll
  for (int cf = 0; cf < 2; ++cf) {
    int col = bn * 32 + cf * 16 + ln15;
    float b0 = bi[col], b1 = bff[col], b2 = bg[col], b3 = bo[col];
    int row0 = bm * 64 + wv * 16 + q * 4;
#pragma unroll
    for (int r = 0; r < 4; ++r) {
      size_t idx = (size_t)(row0 + r) * F_DIM + col;
      float pi = acc[0][cf][r] + b0;
      float pf = acc[1][cf][r] + b1;
      float pg = acc[2][cf][r] + b2;
      float po = acc[3][cf][r] + b3;
      float iv = sigmoid_f(pi);
      float fv = sigmoid_f(pf);
      float gv = tanh_f(pg);
      float ov = sigmoid_f(po);
      float cv = fv * c0[idx] + iv * gv;
      out[idx] = ov * tanh_f(cv);
    }
  }
}

extern "C" void kernel_launch(void* const* d_in, const int* in_sizes, int n_in,
                              void* d_out, int out_size, void* d_ws, size_t ws_size,
                              hipStream_t stream) {
  const float* behavior = (const float*)d_in[0];
  const float* h0       = (const float*)d_in[1];
  const float* c0       = (const float*)d_in[2];
  const float* Wi_h     = (const float*)d_in[3];
  const float* Wi_x     = (const float*)d_in[4];
  const float* bi       = (const float*)d_in[5];
  const float* Wf_h     = (const float*)d_in[6];
  const float* Wf_x     = (const float*)d_in[7];
  const float* bf       = (const float*)d_in[8];
  const float* Wg_h     = (const float*)d_in[9];
  const float* Wg_x     = (const float*)d_in[10];
  const float* bg       = (const float*)d_in[11];
  const float* Wo_h     = (const float*)d_in[12];
  const float* Wo_x     = (const float*)d_in[13];
  const float* bo       = (const float*)d_in[14];
  float* out = (float*)d_out;

  // workspace: Xc (32 MB bf16) + WT (64 MB bf16) = ~96 MiB
  u16* Xc = (u16*)d_ws;
  u16* WT = Xc + (size_t)N_ROWS * K_DIM;

  pack_x_kernel<<<dim3(N_ROWS * (K_DIM / 8) / 256), 256, 0, stream>>>(h0, behavior, Xc);
  pack_w_kernel<<<dim3(F_DIM / 64, K_DIM / 64, 4), 256, 0, stream>>>(
      Wi_h, Wi_x, Wf_h, Wf_x, Wg_h, Wg_x, Wo_h, Wo_x, WT);
  lstm_gemm_kernel<<<dim3(N_ROWS / 64, F_DIM / 32), 256, 0, stream>>>(
      Xc, WT, c0, bi, bf, bg, bo, out);
}

// Round 3
// 508.841 us; speedup vs baseline: 1.1246x; 1.1246x over previous
//
#include <hip/hip_runtime.h>
#include <stdint.h>

#define N_ROWS 4096
#define F_DIM  2048
#define B_DIM  2048
#define K_DIM  4096   // F (h part) + B (behavior part)

typedef __attribute__((ext_vector_type(8)))  __bf16 bf16x8;
typedef __attribute__((ext_vector_type(16))) float  f32x16;
typedef unsigned short u16;

__device__ __forceinline__ u16 f2bf(float x) {
  unsigned int u = __float_as_uint(x);
  u += 0x7fffu + ((u >> 16) & 1u);   // RNE
  return (u16)(u >> 16);
}

__device__ __forceinline__ void async_copy16(const void* g, void* l) {
  __builtin_amdgcn_global_load_lds(
      (const __attribute__((address_space(1))) void*)g,
      (__attribute__((address_space(3))) void*)l, 16, 0, 0);
}

__device__ __forceinline__ float sigmoid_f(float x) {
  return 1.0f / (1.0f + __expf(-x));
}
__device__ __forceinline__ float tanh_f(float x) {
  float e2 = __expf(2.0f * x);
  return 1.0f - 2.0f / (e2 + 1.0f);
}

// ---------------- pack_x: Xc[n][k] = bf16( k<F ? h0[n][k] : behavior[n][k-F] )
__global__ __launch_bounds__(256) void pack_x_kernel(
    const float* __restrict__ h0, const float* __restrict__ behavior,
    u16* __restrict__ Xc)
{
  int tid = blockIdx.x * 256 + threadIdx.x;  // one thread = 8 consecutive k
  int row = tid >> 9;                        // K_DIM/8 = 512 octets per row
  int k0  = (tid & 511) * 8;
  const float* src = (k0 < F_DIM) ? (h0 + (size_t)row * F_DIM + k0)
                                  : (behavior + (size_t)row * B_DIM + (k0 - F_DIM));
  const float4* s4 = (const float4*)src;
  float4 a = s4[0], b = s4[1];
  uint4 o;
  o.x = (unsigned)f2bf(a.x) | ((unsigned)f2bf(a.y) << 16);
  o.y = (unsigned)f2bf(a.z) | ((unsigned)f2bf(a.w) << 16);
  o.z = (unsigned)f2bf(b.x) | ((unsigned)f2bf(b.y) << 16);
  o.w = (unsigned)f2bf(b.z) | ((unsigned)f2bf(b.w) << 16);
  *(uint4*)(Xc + (size_t)tid * 8) = o;
}

// ---------------- pack_w v3: WT[g][f][k] = bf16( k<F ? W?_h[k][f] : W?_x[k-F][f] )
// 32f x 64k tile per block, LDS 8.3 KB (full occupancy). float4 coalesced reads
// -> LDS transpose (pad 65) -> one 16B uint4 store per thread (8 k-contig bf16).
__global__ __launch_bounds__(256) void pack_w_kernel(
    const float* __restrict__ wi_h, const float* __restrict__ wi_x,
    const float* __restrict__ wf_h, const float* __restrict__ wf_x,
    const float* __restrict__ wg_h, const float* __restrict__ wg_x,
    const float* __restrict__ wo_h, const float* __restrict__ wo_x,
    u16* __restrict__ WT)
{
  __shared__ float tileT[32 * 65];  // tileT[f_local][k_local], pad 65
  int g = blockIdx.z;
  const float* Wh = (g == 0) ? wi_h : (g == 1) ? wf_h : (g == 2) ? wg_h : wo_h;
  const float* Wx = (g == 0) ? wi_x : (g == 1) ? wf_x : (g == 2) ? wg_x : wo_x;
  int fb = blockIdx.x * 32;   // feature tile base
  int kb = blockIdx.y * 64;   // k tile base (block-uniform h/x split: 64 | 2048)
  const float* W = (kb < F_DIM) ? Wh : Wx;
  int kofs = (kb < F_DIM) ? kb : (kb - F_DIM);

  int t  = threadIdx.x;
  int c4 = t & 7;          // float4 column within f-tile (8*4 = 32 f)
  int kr = t >> 3;         // 0..31
#pragma unroll
  for (int p = 0; p < 2; ++p) {
    int k_l = kr + p * 32;  // 0..63
    float4 v = *(const float4*)(W + (size_t)(kofs + k_l) * F_DIM + fb + c4 * 4);
    tileT[(c4 * 4 + 0) * 65 + k_l] = v.x;
    tileT[(c4 * 4 + 1) * 65 + k_l] = v.y;
    tileT[(c4 * 4 + 2) * 65 + k_l] = v.z;
    tileT[(c4 * 4 + 3) * 65 + k_l] = v.w;
  }
  __syncthreads();
  {
    int f_l = t >> 3;            // 0..31
    int k8  = (t & 7) * 8;       // 0..56
    const float* s = tileT + f_l * 65 + k8;
    uint4 o;
    o.x = (unsigned)f2bf(s[0]) | ((unsigned)f2bf(s[1]) << 16);
    o.y = (unsigned)f2bf(s[2]) | ((unsigned)f2bf(s[3]) << 16);
    o.z = (unsigned)f2bf(s[4]) | ((unsigned)f2bf(s[5]) << 16);
    o.w = (unsigned)f2bf(s[6]) | ((unsigned)f2bf(s[7]) << 16);
    *(uint4*)(WT + ((size_t)g * F_DIM + fb + f_l) * K_DIM + kb + k8) = o;
  }
}

// ---------------- fused 4-gate GEMM + LSTM epilogue (v3)
// Block: 256 thr = 4 waves. Output tile: 128 rows x (4 gates x 64 f) = 128x256 eff.
// Waves 2x2: rw = w&1 -> rows 64rw..64rw+64; fh = w>>1 -> f-cols 32fh..32fh+32.
// Wave tile 64x128 eff -> LDS bytes/MAC = 2/128 + 2/64 (2x lower than r1/r2).
// MFMA 32x32x16 (higher ceiling 2495 TF). acc = 4g x 2rh x 16 = 128 VGPR.
// LDS: As[128][64] (16 KB) + Bs[4][64][64] (32 KB) = 48 KB, XOR-octet swizzled.
__global__ __launch_bounds__(256, 2) void lstm_gemm_kernel(
    const u16* __restrict__ Xc, const u16* __restrict__ WT,
    const float* __restrict__ c0,
    const float* __restrict__ bi, const float* __restrict__ bff,
    const float* __restrict__ bg, const float* __restrict__ bo,
    float* __restrict__ out)
{
  __shared__ u16 As[128 * 64];      // 16 KB
  __shared__ u16 Bs[4 * 64 * 64];   // 32 KB

  const int tid  = threadIdx.x;
  const int lane = tid & 63;
  const int wv   = tid >> 6;
  const int bm   = blockIdx.x;  // rows bm*128 (x fast-varying -> B-tile L2 reuse)
  const int bn   = blockIdx.y;  // f-cols bn*64

  const int rw = wv & 1;        // row half
  const int fh = wv >> 1;       // f half
  const int l31  = lane & 31;
  const int half = lane >> 5;

  // ---- staging descriptors (16B chunks; XOR-octet swizzle vs row&7)
  const u16* agp[4];
  const u16* bgp[8];
#pragma unroll
  for (int j = 0; j < 4; ++j) {  // A: chunk c = j*256+tid -> row c/8, slot c%8
    int c = j * 256 + tid;
    int r = c >> 3, o = (c & 7) ^ (r & 7);
    agp[j] = Xc + (size_t)(bm * 128 + r) * K_DIM + o * 8;
  }
#pragma unroll
  for (int g = 0; g < 4; ++g)
#pragma unroll
    for (int jj = 0; jj < 2; ++jj) {  // B gate g: 512 chunks over 64 f-rows
      int c = jj * 256 + tid;
      int r = c >> 3, o = (c & 7) ^ (r & 7);
      bgp[g * 2 + jj] = WT + ((size_t)g * F_DIM + bn * 64 + r) * K_DIM + o * 8;
    }
  const unsigned ubase = (unsigned)(tid & ~63) * 16u;  // wave-uniform LDS byte offset

  f32x16 acc[4][2];
#pragma unroll
  for (int g = 0; g < 4; ++g)
#pragma unroll
    for (int rh = 0; rh < 2; ++rh)
#pragma unroll
      for (int r = 0; r < 16; ++r) acc[g][rh][r] = 0.f;

  for (int kt = 0; kt < 64; ++kt) {
#pragma unroll
    for (int j = 0; j < 4; ++j)
      async_copy16(agp[j], (char*)As + j * 4096 + ubase);
#pragma unroll
    for (int j = 0; j < 8; ++j)
      async_copy16(bgp[j], (char*)Bs + (j >> 1) * 8192 + (j & 1) * 4096 + ubase);
#pragma unroll
    for (int j = 0; j < 4; ++j) agp[j] += 64;
#pragma unroll
    for (int j = 0; j < 8; ++j) bgp[j] += 64;
    __syncthreads();  // drains vmcnt -> staging complete

#pragma unroll
    for (int c = 0; c < 4; ++c) {   // four k-chunks of 16 within the 64-k tile
      const int oct = c * 2 + half;
      const int sw  = oct ^ (l31 & 7);   // row&7 == l31&7 for all frags below
      bf16x8 af[2];
#pragma unroll
      for (int rh = 0; rh < 2; ++rh) {
        int m = rw * 64 + rh * 32 + l31;
        af[rh] = *(const bf16x8*)(As + m * 64 + sw * 8);
      }
      bf16x8 bfr[4];
#pragma unroll
      for (int g = 0; g < 4; ++g) {
        int fl = fh * 32 + l31;
        bfr[g] = *(const bf16x8*)(Bs + g * 4096 + fl * 64 + sw * 8);
      }
#pragma unroll
      for (int g = 0; g < 4; ++g)
#pragma unroll
        for (int rh = 0; rh < 2; ++rh)
          acc[g][rh] = __builtin_amdgcn_mfma_f32_32x32x16_bf16(
              af[rh], bfr[g], acc[g][rh], 0, 0, 0);
    }
    __syncthreads();  // all waves done reading before next overwrite
  }

  // ---- epilogue: 32x32 C/D layout: col = lane&31, row = (r&3) + 8*(r>>2) + 4*half
  {
    int f = bn * 64 + fh * 32 + l31;
    float b0 = bi[f], b1 = bff[f], b2 = bg[f], b3 = bo[f];
#pragma unroll
    for (int rh = 0; rh < 2; ++rh) {
      int row_base = bm * 128 + rw * 64 + rh * 32 + 4 * half;
#pragma unroll
      for (int r = 0; r < 16; ++r) {
        int row = row_base + (r & 3) + 8 * (r >> 2);
        size_t idx = (size_t)row * F_DIM + f;
        float pi = acc[0][rh][r] + b0;
        float pf = acc[1][rh][r] + b1;
        float pg = acc[2][rh][r] + b2;
        float po = acc[3][rh][r] + b3;
        float iv = sigmoid_f(pi);
        float fv = sigmoid_f(pf);
        float gv = tanh_f(pg);
        float ov = sigmoid_f(po);
        float cv = fv * c0[idx] + iv * gv;
        out[idx] = ov * tanh_f(cv);
      }
    }
  }
}

extern "C" void kernel_launch(void* const* d_in, const int* in_sizes, int n_in,
                              void* d_out, int out_size, void* d_ws, size_t ws_size,
                              hipStream_t stream) {
  const float* behavior = (const float*)d_in[0];
  const float* h0       = (const float*)d_in[1];
  const float* c0       = (const float*)d_in[2];
  const float* Wi_h     = (const float*)d_in[3];
  const float* Wi_x     = (const float*)d_in[4];
  const float* bi       = (const float*)d_in[5];
  const float* Wf_h     = (const float*)d_in[6];
  const float* Wf_x     = (const float*)d_in[7];
  const float* bf       = (const float*)d_in[8];
  const float* Wg_h     = (const float*)d_in[9];
  const float* Wg_x     = (const float*)d_in[10];
  const float* bg       = (const float*)d_in[11];
  const float* Wo_h     = (const float*)d_in[12];
  const float* Wo_x     = (const float*)d_in[13];
  const float* bo       = (const float*)d_in[14];
  float* out = (float*)d_out;

  // workspace: Xc (32 MB bf16) + WT (64 MB bf16) = ~96 MiB
  u16* Xc = (u16*)d_ws;
  u16* WT = Xc + (size_t)N_ROWS * K_DIM;

  pack_x_kernel<<<dim3(N_ROWS * (K_DIM / 8) / 256), 256, 0, stream>>>(h0, behavior, Xc);
  pack_w_kernel<<<dim3(F_DIM / 32, K_DIM / 64, 4), 256, 0, stream>>>(
      Wi_h, Wi_x, Wf_h, Wf_x, Wg_h, Wg_x, Wo_h, Wo_x, WT);
  lstm_gemm_kernel<<<dim3(N_ROWS / 128, F_DIM / 64), 256, 0, stream>>>(
      Xc, WT, c0, bi, bf, bg, bo, out);
}